// Round 1
// baseline (198.745 us; speedup 1.0000x reference)
//
#include <hip/hip_runtime.h>
#include <hip/hip_bf16.h>
#include <cstdint>

#define B_   2
#define T_   2048
#define C_   1024
#define NH_  16
#define HS_  64
#define WIN_ 256
#define M_   (B_*T_)   // 4096

typedef __attribute__((ext_vector_type(8))) short          short8;
typedef __attribute__((ext_vector_type(8))) unsigned short ushortx8;
typedef __attribute__((ext_vector_type(8))) __bf16         bf16x8;
typedef __attribute__((ext_vector_type(4))) float          floatx4;

__device__ __forceinline__ unsigned short f2bf(float f) {
    union { float f; uint32_t u; } v; v.f = f;
    uint32_t r = (v.u + 0x7FFFu + ((v.u >> 16) & 1u)) >> 16;
    return (unsigned short)r;
}

__device__ __forceinline__ floatx4 mfma16(short8 a, short8 b, floatx4 c) {
    return __builtin_amdgcn_mfma_f32_16x16x32_bf16(
        __builtin_bit_cast(bf16x8, a), __builtin_bit_cast(bf16x8, b), c, 0, 0, 0);
}

// ---------------------------------------------------------------------------
// GEMM: C[M,N] = A[M,K] @ B[K,N].  A fp32 or bf16, B fp32 (converted to bf16
// in staging), accumulate fp32, output fp32 or bf16.
// 128x128 tile, BK=32, 256 threads (4 waves, each 64x64 via 4x4 16x16x32 MFMA)
// ---------------------------------------------------------------------------
template<bool A_IS_BF16, bool OUT_BF16>
__global__ __launch_bounds__(256)
void gemm_mfma(const void* __restrict__ Ap, const float* __restrict__ Bm,
               void* __restrict__ Cp, int M, int N, int K)
{
    constexpr int BM = 128, BN = 128, BK = 32, PK = 40;  // PK: +8 pad (2-way = free)
    __shared__ unsigned short As[BM * PK];   // [m][k]
    __shared__ unsigned short Bs[BN * PK];   // [n][k] (transposed)

    const int tid  = threadIdx.x;
    const int lane = tid & 63;
    const int wave = tid >> 6;
    const int l16  = lane & 15;
    const int quad = lane >> 4;
    const int wm   = (wave & 1) * 64;
    const int wn   = (wave >> 1) * 64;
    const int m0   = blockIdx.y * BM;
    const int n0   = blockIdx.x * BN;

    floatx4 acc[4][4];
    #pragma unroll
    for (int i = 0; i < 4; i++)
        #pragma unroll
        for (int j = 0; j < 4; j++) acc[i][j] = (floatx4){0.f, 0.f, 0.f, 0.f};

    // B staging mapping: thread owns one column (n) and a 16-wide k half
    const int bn = tid & 127;
    const int bh = (tid >> 7) * 16;

    for (int k0 = 0; k0 < K; k0 += BK) {
        // ---- stage A tile -> As[m][k] ----
        if (A_IS_BF16) {
            const unsigned short* A = (const unsigned short*)Ap;
            #pragma unroll
            for (int it = 0; it < 4; it++) {
                int c = tid + 256 * it;
                int row = c >> 3, kc = (c & 7) << 2;
                ushort4 v = *(const ushort4*)(&A[(size_t)(m0 + row) * K + k0 + kc]);
                *(ushort4*)(&As[row * PK + kc]) = v;
            }
        } else {
            const float* A = (const float*)Ap;
            #pragma unroll
            for (int it = 0; it < 4; it++) {
                int c = tid + 256 * it;
                int row = c >> 3, kc = (c & 7) << 2;
                float4 v = *(const float4*)(&A[(size_t)(m0 + row) * K + k0 + kc]);
                ushort4 h;
                h.x = f2bf(v.x); h.y = f2bf(v.y); h.z = f2bf(v.z); h.w = f2bf(v.w);
                *(ushort4*)(&As[row * PK + kc]) = h;
            }
        }
        // ---- stage B tile -> Bs[n][k] (transposed) ----
        {
            ushortx8 w0, w1;
            #pragma unroll
            for (int j = 0; j < 8; j++)
                w0[j] = f2bf(Bm[(size_t)(k0 + bh + j) * N + n0 + bn]);
            #pragma unroll
            for (int j = 0; j < 8; j++)
                w1[j] = f2bf(Bm[(size_t)(k0 + bh + 8 + j) * N + n0 + bn]);
            *(ushortx8*)(&Bs[bn * PK + bh])     = w0;
            *(ushortx8*)(&Bs[bn * PK + bh + 8]) = w1;
        }
        __syncthreads();

        // ---- compute ----
        short8 af[4], bfr[4];
        #pragma unroll
        for (int i = 0; i < 4; i++)
            af[i] = *(const short8*)(&As[(wm + i * 16 + l16) * PK + quad * 8]);
        #pragma unroll
        for (int j = 0; j < 4; j++)
            bfr[j] = *(const short8*)(&Bs[(wn + j * 16 + l16) * PK + quad * 8]);
        #pragma unroll
        for (int i = 0; i < 4; i++)
            #pragma unroll
            for (int j = 0; j < 4; j++)
                acc[i][j] = mfma16(af[i], bfr[j], acc[i][j]);
        __syncthreads();
    }

    // ---- epilogue: C/D layout col=l16, row=quad*4+r ----
    #pragma unroll
    for (int i = 0; i < 4; i++)
        #pragma unroll
        for (int j = 0; j < 4; j++)
            #pragma unroll
            for (int r = 0; r < 4; r++) {
                int row = m0 + wm + i * 16 + quad * 4 + r;
                int col = n0 + wn + j * 16 + l16;
                if (OUT_BF16)
                    ((unsigned short*)Cp)[(size_t)row * N + col] = f2bf(acc[i][j][r]);
                else
                    ((float*)Cp)[(size_t)row * N + col] = acc[i][j][r];
            }
}

// ---------------------------------------------------------------------------
// Sliding-window causal attention, flash-style online softmax.
// Block = (64 q-rows, one head, one batch). 4 waves, each owns 16 q-rows.
// qkv: bf16 [M][3C] rows; y: bf16 [M][C].
// ---------------------------------------------------------------------------
__global__ __launch_bounds__(256)
void attn_kernel(const unsigned short* __restrict__ qkv, unsigned short* __restrict__ y)
{
    constexpr int PD = 72;  // 64 + 8 pad
    __shared__ unsigned short Qs[64 * PD];      // [q][d]
    __shared__ unsigned short Ks[64 * PD];      // [key][d]
    __shared__ unsigned short Vt[64 * PD];      // [d][key] (transposed)
    __shared__ unsigned short Ps[4][16 * PD];   // per-wave P [q][key]

    const int tid  = threadIdx.x;
    const int lane = tid & 63;
    const int wave = tid >> 6;
    const int l16  = lane & 15;
    const int quad = lane >> 4;

    const int q0 = blockIdx.x * 64;   // within T
    const int h  = blockIdx.y;
    const int b  = blockIdx.z;
    const size_t base = (size_t)b * T_;
    const int ROW = 3 * C_;
    const int qoff = h * HS_;
    const int koff = C_ + h * HS_;
    const int voff = 2 * C_ + h * HS_;

    // load Q tile
    #pragma unroll
    for (int it = 0; it < 4; it++) {
        int c = tid + 256 * it;
        int row = c >> 4, dc = (c & 15) << 2;
        *(ushort4*)(&Qs[row * PD + dc]) =
            *(const ushort4*)(&qkv[(base + q0 + row) * ROW + qoff + dc]);
    }

    floatx4 O[4];
    #pragma unroll
    for (int j = 0; j < 4; j++) O[j] = (floatx4){0.f, 0.f, 0.f, 0.f};
    float m_i[4], l_i[4];
    #pragma unroll
    for (int r = 0; r < 4; r++) { m_i[r] = -1e30f; l_i[r] = 0.f; }

    const int vd = tid & 63;          // V-transpose: column owned
    const int vk = (tid >> 6) * 16;   // and 16-key chunk

    const int kb_lo = (q0 - WIN_) > 0 ? (q0 - WIN_) : 0;
    for (int kb = kb_lo; kb <= q0; kb += 64) {
        __syncthreads();  // protect Ks/Vt from previous iteration readers
        // stage K tile [key][d]
        #pragma unroll
        for (int it = 0; it < 4; it++) {
            int c = tid + 256 * it;
            int row = c >> 4, dc = (c & 15) << 2;
            *(ushort4*)(&Ks[row * PD + dc]) =
                *(const ushort4*)(&qkv[(base + kb + row) * ROW + koff + dc]);
        }
        // stage V tile transposed -> Vt[d][key]
        {
            ushortx8 w0, w1;
            #pragma unroll
            for (int j = 0; j < 8; j++)
                w0[j] = qkv[(base + kb + vk + j) * ROW + voff + vd];
            #pragma unroll
            for (int j = 0; j < 8; j++)
                w1[j] = qkv[(base + kb + vk + 8 + j) * ROW + voff + vd];
            *(ushortx8*)(&Vt[vd * PD + vk])     = w0;
            *(ushortx8*)(&Vt[vd * PD + vk + 8]) = w1;
        }
        __syncthreads();

        // ---- S = Q K^T (16q x 64k per wave) ----
        floatx4 s[4];
        #pragma unroll
        for (int nt = 0; nt < 4; nt++) s[nt] = (floatx4){0.f, 0.f, 0.f, 0.f};
        #pragma unroll
        for (int ks = 0; ks < 2; ks++) {
            short8 a = *(const short8*)(&Qs[(wave * 16 + l16) * PD + ks * 32 + quad * 8]);
            #pragma unroll
            for (int nt = 0; nt < 4; nt++) {
                short8 bb = *(const short8*)(&Ks[(nt * 16 + l16) * PD + ks * 32 + quad * 8]);
                s[nt] = mfma16(a, bb, s[nt]);
            }
        }

        // ---- mask + scale; tile row max ----
        const int qrb = q0 + wave * 16 + quad * 4;
        float mt[4] = {-1e30f, -1e30f, -1e30f, -1e30f};
        #pragma unroll
        for (int nt = 0; nt < 4; nt++)
            #pragma unroll
            for (int r = 0; r < 4; r++) {
                int qa = qrb + r;
                int ka = kb + nt * 16 + l16;
                float val = s[nt][r] * 0.125f;
                bool ok = (ka <= qa) && (qa - ka < WIN_);
                val = ok ? val : -1e30f;
                s[nt][r] = val;
                mt[r] = fmaxf(mt[r], val);
            }
        #pragma unroll
        for (int r = 0; r < 4; r++) {
            #pragma unroll
            for (int off = 8; off >= 1; off >>= 1)
                mt[r] = fmaxf(mt[r], __shfl_xor(mt[r], off, 64));
        }

        // ---- online softmax update ----
        float alpha[4];
        #pragma unroll
        for (int r = 0; r < 4; r++) {
            float mnew = fmaxf(m_i[r], mt[r]);
            alpha[r] = __expf(m_i[r] - mnew);
            m_i[r] = mnew;
        }
        float psum[4] = {0.f, 0.f, 0.f, 0.f};
        #pragma unroll
        for (int nt = 0; nt < 4; nt++)
            #pragma unroll
            for (int r = 0; r < 4; r++) {
                float p = (s[nt][r] > -1e29f) ? __expf(s[nt][r] - m_i[r]) : 0.f;
                s[nt][r] = p;
                psum[r] += p;
            }
        #pragma unroll
        for (int r = 0; r < 4; r++) {
            #pragma unroll
            for (int off = 8; off >= 1; off >>= 1)
                psum[r] += __shfl_xor(psum[r], off, 64);
            l_i[r] = l_i[r] * alpha[r] + psum[r];
        }
        #pragma unroll
        for (int jt = 0; jt < 4; jt++)
            #pragma unroll
            for (int r = 0; r < 4; r++) O[jt][r] *= alpha[r];

        // ---- P: C-layout -> LDS [q][key] (A-layout source) ----
        #pragma unroll
        for (int nt = 0; nt < 4; nt++)
            #pragma unroll
            for (int r = 0; r < 4; r++)
                Ps[wave][(quad * 4 + r) * PD + nt * 16 + l16] = f2bf(s[nt][r]);

        // ---- O += P @ V ----
        #pragma unroll
        for (int ks = 0; ks < 2; ks++) {
            short8 a = *(const short8*)(&Ps[wave][l16 * PD + ks * 32 + quad * 8]);
            #pragma unroll
            for (int jt = 0; jt < 4; jt++) {
                short8 bb = *(const short8*)(&Vt[(jt * 16 + l16) * PD + ks * 32 + quad * 8]);
                O[jt] = mfma16(a, bb, O[jt]);
            }
        }
    }

    // ---- write y[q][h*64+d] ----
    #pragma unroll
    for (int jt = 0; jt < 4; jt++)
        #pragma unroll
        for (int r = 0; r < 4; r++) {
            int qa = q0 + wave * 16 + quad * 4 + r;
            float o = O[jt][r] / l_i[r];
            y[(base + qa) * C_ + h * HS_ + jt * 16 + l16] = f2bf(o);
        }
}

// ---------------------------------------------------------------------------
extern "C" void kernel_launch(void* const* d_in, const int* in_sizes, int n_in,
                              void* d_out, int out_size, void* d_ws, size_t ws_size,
                              hipStream_t stream)
{
    const float* x      = (const float*)d_in[0];
    const float* W_attn = (const float*)d_in[1];
    const float* W_proj = (const float*)d_in[2];
    float* out = (float*)d_out;

    unsigned short* qkv = (unsigned short*)d_ws;                    // M x 3C bf16
    unsigned short* y   = qkv + (size_t)M_ * 3 * C_;                // M x C bf16

    dim3 blk(256);
    gemm_mfma<false, true><<<dim3((3 * C_) / 128, M_ / 128), blk, 0, stream>>>(
        x, W_attn, qkv, M_, 3 * C_, C_);
    attn_kernel<<<dim3(T_ / 64, NH_, B_), blk, 0, stream>>>(qkv, y);
    gemm_mfma<true, false><<<dim3(C_ / 128, M_ / 128), blk, 0, stream>>>(
        y, W_proj, out, M_, C_, C_);
}

// Round 2
// 181.534 us; speedup vs baseline: 1.0948x; 1.0948x over previous
//
#include <hip/hip_runtime.h>
#include <hip/hip_bf16.h>
#include <cstdint>

#define B_   2
#define T_   2048
#define C_   1024
#define NH_  16
#define HS_  64
#define WIN_ 256
#define M_   (B_*T_)   // 4096

typedef __attribute__((ext_vector_type(8))) short          short8;
typedef __attribute__((ext_vector_type(8))) unsigned short ushortx8;
typedef __attribute__((ext_vector_type(8))) __bf16         bf16x8;
typedef __attribute__((ext_vector_type(4))) float          floatx4;

__device__ __forceinline__ unsigned short f2bf(float f) {
    union { float f; uint32_t u; } v; v.f = f;
    uint32_t r = (v.u + 0x7FFFu + ((v.u >> 16) & 1u)) >> 16;
    return (unsigned short)r;
}

__device__ __forceinline__ floatx4 mfma16(short8 a, short8 b, floatx4 c) {
    return __builtin_amdgcn_mfma_f32_16x16x32_bf16(
        __builtin_bit_cast(bf16x8, a), __builtin_bit_cast(bf16x8, b), c, 0, 0, 0);
}

// async global -> LDS, 16 bytes per lane (wave-uniform LDS base + lane*16)
__device__ __forceinline__ void async16(const void* g, void* l) {
    __builtin_amdgcn_global_load_lds(
        (const __attribute__((address_space(1))) void*)g,
        (__attribute__((address_space(3))) void*)l, 16, 0, 0);
}

// ---------------------------------------------------------------------------
// prep: fp32 -> bf16 elementwise (x)
// ---------------------------------------------------------------------------
__global__ __launch_bounds__(256)
void convert_bf16(const float* __restrict__ in, unsigned short* __restrict__ out)
{
    int i = (blockIdx.x * 256 + threadIdx.x) * 4;
    float4 v = *(const float4*)&in[i];
    ushort4 h;
    h.x = f2bf(v.x); h.y = f2bf(v.y); h.z = f2bf(v.z); h.w = f2bf(v.w);
    *(ushort4*)&out[i] = h;
}

// ---------------------------------------------------------------------------
// prep: fp32 [K][N] -> bf16 [N][K] (weight transpose+convert), 64x64 tiles
// ---------------------------------------------------------------------------
__global__ __launch_bounds__(256)
void transpose_convert(const float* __restrict__ in, unsigned short* __restrict__ out,
                       int K, int N)
{
    __shared__ unsigned short tile[64][72];
    const int k0 = blockIdx.y * 64, n0 = blockIdx.x * 64;
    const int tr = threadIdx.x >> 4;          // 0..15
    const int tc = (threadIdx.x & 15) * 4;    // 0..60
    #pragma unroll
    for (int it = 0; it < 4; it++) {
        int row = tr + it * 16;
        float4 v = *(const float4*)&in[(size_t)(k0 + row) * N + n0 + tc];
        ushort4 h;
        h.x = f2bf(v.x); h.y = f2bf(v.y); h.z = f2bf(v.z); h.w = f2bf(v.w);
        *(ushort4*)&tile[row][tc] = h;
    }
    __syncthreads();
    #pragma unroll
    for (int it = 0; it < 4; it++) {
        int nrow = tr + it * 16;
        ushort4 h;
        h.x = tile[tc + 0][nrow]; h.y = tile[tc + 1][nrow];
        h.z = tile[tc + 2][nrow]; h.w = tile[tc + 3][nrow];
        *(ushort4*)&out[(size_t)(n0 + nrow) * K + k0 + tc] = h;
    }
}

// ---------------------------------------------------------------------------
// m97-style GEMM: C[M,N] = A[M,K] @ Bt[N,K]^T, bf16 in, fp32 acc.
// 128x128 tile, BK=32, global_load_lds(16B) staging, unpadded LDS.
// ---------------------------------------------------------------------------
template<bool OUT_BF16>
__global__ __launch_bounds__(256)
void gemm_bt(const unsigned short* __restrict__ A,   // [M][K]
             const unsigned short* __restrict__ Bt,  // [N][K]
             void* __restrict__ Cp, int M, int N, int K)
{
    constexpr int BK = 32;
    __shared__ unsigned short As[128 * BK];   // 8 KB, [m][k] contiguous
    __shared__ unsigned short Bs[128 * BK];   // 8 KB, [n][k] contiguous

    const int tid  = threadIdx.x;
    const int lane = tid & 63;
    const int wave = tid >> 6;
    const int l16  = lane & 15;
    const int quad = lane >> 4;
    const int wm   = (wave & 1) * 64;
    const int wn   = (wave >> 1) * 64;
    const int m0   = blockIdx.y * 128;
    const int n0   = blockIdx.x * 128;

    // staging: lane covers row = wave*16 + (lane>>2), col = (lane&3)*8
    const int srow = wave * 16 + (lane >> 2);
    const int scol = (lane & 3) * 8;

    floatx4 acc[4][4];
    #pragma unroll
    for (int i = 0; i < 4; i++)
        #pragma unroll
        for (int j = 0; j < 4; j++) acc[i][j] = (floatx4){0.f, 0.f, 0.f, 0.f};

    const unsigned short* gA = &A[(size_t)(m0 + srow) * K + scol];
    const unsigned short* gB = &Bt[(size_t)(n0 + srow) * K + scol];
    unsigned short* lA = &As[wave * 16 * BK];
    unsigned short* lB = &Bs[wave * 16 * BK];

    for (int k0 = 0; k0 < K; k0 += BK) {
        async16(gA + k0,            lA);
        async16(gA + k0 + 64 * K,   lA + 64 * BK);
        async16(gB + k0,            lB);
        async16(gB + k0 + 64 * K,   lB + 64 * BK);
        __syncthreads();

        short8 af[4], bfr[4];
        #pragma unroll
        for (int i = 0; i < 4; i++)
            af[i] = *(const short8*)(&As[(wm + i * 16 + l16) * BK + quad * 8]);
        #pragma unroll
        for (int j = 0; j < 4; j++)
            bfr[j] = *(const short8*)(&Bs[(wn + j * 16 + l16) * BK + quad * 8]);
        #pragma unroll
        for (int i = 0; i < 4; i++)
            #pragma unroll
            for (int j = 0; j < 4; j++)
                acc[i][j] = mfma16(af[i], bfr[j], acc[i][j]);
        __syncthreads();
    }

    #pragma unroll
    for (int i = 0; i < 4; i++)
        #pragma unroll
        for (int j = 0; j < 4; j++)
            #pragma unroll
            for (int r = 0; r < 4; r++) {
                int row = m0 + wm + i * 16 + quad * 4 + r;
                int col = n0 + wn + j * 16 + l16;
                if (OUT_BF16)
                    ((unsigned short*)Cp)[(size_t)row * N + col] = f2bf(acc[i][j][r]);
                else
                    ((float*)Cp)[(size_t)row * N + col] = acc[i][j][r];
            }
}

// ---------------------------------------------------------------------------
// Sliding-window causal attention, flash-style online softmax.
// Block = (64 q-rows, one head, one batch). 4 waves, each owns 16 q-rows.
// ---------------------------------------------------------------------------
__global__ __launch_bounds__(256)
void attn_kernel(const unsigned short* __restrict__ qkv, unsigned short* __restrict__ y)
{
    constexpr int PD = 72;
    __shared__ unsigned short Qs[64 * PD];      // [q][d]
    __shared__ unsigned short Ks[64 * PD];      // [key][d]
    __shared__ unsigned short Vt[64 * PD];      // [d][key] (transposed)
    __shared__ unsigned short Ps[4][16 * PD];   // per-wave P [q][key]

    const int tid  = threadIdx.x;
    const int lane = tid & 63;
    const int wave = tid >> 6;
    const int l16  = lane & 15;
    const int quad = lane >> 4;

    const int q0 = blockIdx.x * 64;
    const int h  = blockIdx.y;
    const int b  = blockIdx.z;
    const size_t base = (size_t)b * T_;
    const int ROW = 3 * C_;
    const int qoff = h * HS_;
    const int koff = C_ + h * HS_;
    const int voff = 2 * C_ + h * HS_;

    #pragma unroll
    for (int it = 0; it < 4; it++) {
        int c = tid + 256 * it;
        int row = c >> 4, dc = (c & 15) << 2;
        *(ushort4*)(&Qs[row * PD + dc]) =
            *(const ushort4*)(&qkv[(base + q0 + row) * ROW + qoff + dc]);
    }

    floatx4 O[4];
    #pragma unroll
    for (int j = 0; j < 4; j++) O[j] = (floatx4){0.f, 0.f, 0.f, 0.f};
    float m_i[4], l_i[4];
    #pragma unroll
    for (int r = 0; r < 4; r++) { m_i[r] = -1e30f; l_i[r] = 0.f; }

    const int kb_lo = (q0 - WIN_) > 0 ? (q0 - WIN_) : 0;
    for (int kb = kb_lo; kb <= q0; kb += 64) {
        __syncthreads();
        // stage K tile [key][d] — coalesced ushort4
        #pragma unroll
        for (int it = 0; it < 4; it++) {
            int c = tid + 256 * it;
            int row = c >> 4, dc = (c & 15) << 2;
            *(ushort4*)(&Ks[row * PD + dc]) =
                *(const ushort4*)(&qkv[(base + kb + row) * ROW + koff + dc]);
        }
        // stage V transposed: coalesced ushort8 loads, scalar LDS scatter
        #pragma unroll
        for (int it = 0; it < 2; it++) {
            int c = tid + 256 * it;
            int row = c >> 3, db = (c & 7) * 8;
            ushortx8 v = *(const ushortx8*)&qkv[(base + kb + row) * ROW + voff + db];
            #pragma unroll
            for (int e = 0; e < 8; e++)
                Vt[(db + e) * PD + row] = v[e];
        }
        __syncthreads();

        // ---- S = Q K^T (16q x 64k per wave) ----
        floatx4 s[4];
        #pragma unroll
        for (int nt = 0; nt < 4; nt++) s[nt] = (floatx4){0.f, 0.f, 0.f, 0.f};
        #pragma unroll
        for (int ks = 0; ks < 2; ks++) {
            short8 a = *(const short8*)(&Qs[(wave * 16 + l16) * PD + ks * 32 + quad * 8]);
            #pragma unroll
            for (int nt = 0; nt < 4; nt++) {
                short8 bb = *(const short8*)(&Ks[(nt * 16 + l16) * PD + ks * 32 + quad * 8]);
                s[nt] = mfma16(a, bb, s[nt]);
            }
        }

        const int qrb = q0 + wave * 16 + quad * 4;
        float mt[4] = {-1e30f, -1e30f, -1e30f, -1e30f};
        #pragma unroll
        for (int nt = 0; nt < 4; nt++)
            #pragma unroll
            for (int r = 0; r < 4; r++) {
                int qa = qrb + r;
                int ka = kb + nt * 16 + l16;
                float val = s[nt][r] * 0.125f;
                bool ok = (ka <= qa) && (qa - ka < WIN_);
                val = ok ? val : -1e30f;
                s[nt][r] = val;
                mt[r] = fmaxf(mt[r], val);
            }
        #pragma unroll
        for (int r = 0; r < 4; r++) {
            #pragma unroll
            for (int off = 8; off >= 1; off >>= 1)
                mt[r] = fmaxf(mt[r], __shfl_xor(mt[r], off, 64));
        }

        float alpha[4];
        #pragma unroll
        for (int r = 0; r < 4; r++) {
            float mnew = fmaxf(m_i[r], mt[r]);
            alpha[r] = __expf(m_i[r] - mnew);
            m_i[r] = mnew;
        }
        float psum[4] = {0.f, 0.f, 0.f, 0.f};
        #pragma unroll
        for (int nt = 0; nt < 4; nt++)
            #pragma unroll
            for (int r = 0; r < 4; r++) {
                float p = (s[nt][r] > -1e29f) ? __expf(s[nt][r] - m_i[r]) : 0.f;
                s[nt][r] = p;
                psum[r] += p;
            }
        #pragma unroll
        for (int r = 0; r < 4; r++) {
            #pragma unroll
            for (int off = 8; off >= 1; off >>= 1)
                psum[r] += __shfl_xor(psum[r], off, 64);
            l_i[r] = l_i[r] * alpha[r] + psum[r];
        }
        #pragma unroll
        for (int jt = 0; jt < 4; jt++)
            #pragma unroll
            for (int r = 0; r < 4; r++) O[jt][r] *= alpha[r];

        #pragma unroll
        for (int nt = 0; nt < 4; nt++)
            #pragma unroll
            for (int r = 0; r < 4; r++)
                Ps[wave][(quad * 4 + r) * PD + nt * 16 + l16] = f2bf(s[nt][r]);

        #pragma unroll
        for (int ks = 0; ks < 2; ks++) {
            short8 a = *(const short8*)(&Ps[wave][l16 * PD + ks * 32 + quad * 8]);
            #pragma unroll
            for (int jt = 0; jt < 4; jt++) {
                short8 bb = *(const short8*)(&Vt[(jt * 16 + l16) * PD + ks * 32 + quad * 8]);
                O[jt] = mfma16(a, bb, O[jt]);
            }
        }
    }

    #pragma unroll
    for (int jt = 0; jt < 4; jt++)
        #pragma unroll
        for (int r = 0; r < 4; r++) {
            int qa = q0 + wave * 16 + quad * 4 + r;
            float o = O[jt][r] / l_i[r];
            y[(base + qa) * C_ + h * HS_ + jt * 16 + l16] = f2bf(o);
        }
}

// ---------------------------------------------------------------------------
extern "C" void kernel_launch(void* const* d_in, const int* in_sizes, int n_in,
                              void* d_out, int out_size, void* d_ws, size_t ws_size,
                              hipStream_t stream)
{
    const float* x      = (const float*)d_in[0];
    const float* W_attn = (const float*)d_in[1];
    const float* W_proj = (const float*)d_in[2];
    float* out = (float*)d_out;

    unsigned short* xb   = (unsigned short*)d_ws;                 // [M][C]      8 MB
    unsigned short* Wa_t = xb   + (size_t)M_ * C_;                // [3C][C]     6 MB
    unsigned short* Wp_t = Wa_t + (size_t)3 * C_ * C_;            // [C][C]      2 MB
    unsigned short* qkv  = Wp_t + (size_t)C_ * C_;                // [M][3C]    24 MB
    unsigned short* y    = qkv  + (size_t)M_ * 3 * C_;            // [M][C]      8 MB

    dim3 blk(256);
    convert_bf16<<<(M_ * C_) / 1024, blk, 0, stream>>>(x, xb);
    transpose_convert<<<dim3((3 * C_) / 64, C_ / 64), blk, 0, stream>>>(W_attn, Wa_t, C_, 3 * C_);
    transpose_convert<<<dim3(C_ / 64, C_ / 64), blk, 0, stream>>>(W_proj, Wp_t, C_, C_);

    gemm_bt<true><<<dim3((3 * C_) / 128, M_ / 128), blk, 0, stream>>>(
        xb, Wa_t, qkv, M_, 3 * C_, C_);
    attn_kernel<<<dim3(T_ / 64, NH_, B_), blk, 0, stream>>>(qkv, y);
    gemm_bt<false><<<dim3(C_ / 128, M_ / 128), blk, 0, stream>>>(
        y, Wp_t, out, M_, C_, C_);
}